// Round 4
// baseline (51.524 us; speedup 1.0000x reference)
//
#include <hip/hip_runtime.h>
#include <hip/hip_bf16.h>
#include <math.h>

// BlockwiseDense: y[b,i,j,k] = sum_l quant(relu(cores[i,j,k,l])) * x[b, j*256+l]
// x: (128, 4096) f32, cores: (16,16,256,256) f32, out: (128,16,16,256) f32.
//
// v3b: barrier-free / LDS-free. Each wave owns (i, j, 16 k-rows):
//   A = W fragments loaded straight from global in MFMA layout, quantized
//   in-register (analytic level pair via exp2f — no LUT, no LDS);
//   B = x pre-converted to bf16 once (kernel 1, in d_ws, L2-resident).
// Grid 1024 x 256thr (4 independent waves/WG), no __syncthreads anywhere.

typedef __attribute__((ext_vector_type(4))) float f32x4;
typedef __attribute__((ext_vector_type(8))) short bf16x8;  // 8 bf16
typedef __attribute__((ext_vector_type(8))) short s16x8;

#define TAU   0.75f
#define G_INF 2.0f
#define G_MIN 0.001f

__device__ __forceinline__ short f2bf_rne(float f) {
    union { float f; unsigned u; } v; v.f = f;
    unsigned u = v.u;
    return (short)((u + 0x7FFFu + ((u >> 16) & 1u)) >> 16);
}

// ---- kernel 1: x f32 -> bf16 (1 MB, L2-resident thereafter) ----
__global__ __launch_bounds__(256)
void xcvt(const float* __restrict__ xin, short* __restrict__ xbf) {
    int idx = (blockIdx.x * 256 + threadIdx.x) * 8;
    f32x4 a = *(const f32x4*)(xin + idx);
    f32x4 b = *(const f32x4*)(xin + idx + 4);
    s16x8 o;
    o[0] = f2bf_rne(a[0]); o[1] = f2bf_rne(a[1]);
    o[2] = f2bf_rne(a[2]); o[3] = f2bf_rne(a[3]);
    o[4] = f2bf_rne(b[0]); o[5] = f2bf_rne(b[1]);
    o[6] = f2bf_rne(b[2]); o[7] = f2bf_rne(b[3]);
    *(s16x8*)(xbf + idx) = o;
}

// ---- kernel 2: fused quantize + blockwise GEMM, wave-independent ----
template<bool XBF>
__global__ __launch_bounds__(256, 4)
void bd_fused(const float* __restrict__ x,
              const short* __restrict__ xbf,
              const float* __restrict__ cores,
              float* __restrict__ out)
{
    const int tid  = threadIdx.x;
    const int wave = tid >> 6;
    const int lane = tid & 63;
    const int l15  = lane & 15;
    const int l4   = lane >> 4;

    const int bid = blockIdx.x;
    const int ns  = bid & 3;          // which 64-k slice
    const int j   = (bid >> 2) & 15;  // input block
    const int i   = bid >> 6;         // output block
    const int k0  = ns * 64 + wave * 16;  // this wave's 16 k-rows

    // quantization constants (f32 op order mirrors the numpy reference)
    const float scale     = (G_INF - G_MIN) / (1.0f - expf(-TAU));
    const float inv_scale = 1.0f / scale;
    const float kn = -(255.0f / TAU) * 0.69314718055994531f;   // n = kn*log2(t)
    const float c2 = -(TAU / 255.0f) * 1.44269504088896341f;   // e_f = exp2(c2*f)
    const float Ac = G_MIN + scale;                            // lo = Ac - scale*e_f
    const float Bc = scale * (1.0f - expf(-TAU / 255.0f));     // hi = lo + Bc*e_f

    // ---- A (W): load 16 rows x 256 l directly in fragment layout, quantize ----
    // lane (l15,l4): row k0+l15, cols s*32 + l4*8 .. +7  (4 lanes = 128B/row)
    const float* wrow = cores + (((size_t)(i * 16 + j)) << 16)
                              + (size_t)(k0 + l15) * 256 + l4 * 8;
    bf16x8 afr[8];
    #pragma unroll
    for (int h = 0; h < 2; ++h) {           // two half-batches: 8 loads in flight
        f32x4 wv[4][2];
        #pragma unroll
        for (int s4 = 0; s4 < 4; ++s4) {
            const float* p = wrow + (h * 4 + s4) * 32;
            wv[s4][0] = *(const f32x4*)p;
            wv[s4][1] = *(const f32x4*)(p + 4);
        }
        #pragma unroll
        for (int s4 = 0; s4 < 4; ++s4) {
            bf16x8 a;
            #pragma unroll
            for (int e = 0; e < 8; ++e) {
                float w = fmaxf(wv[s4][e >> 2][e & 3], 0.0f);
                float t = 1.0f - (w - G_MIN) * inv_scale;  // = exp(-tau*n/255)
                t = fmaxf(t, 1e-8f);
                float nr = kn * __log2f(t);
                int f = (int)floorf(nr);
                f = f < 0 ? 0 : (f > 254 ? 254 : f);
                float ef = exp2f(c2 * (float)f);           // v_exp_f32
                float lo = Ac - scale * ef;                // level[f]
                float hi = lo + Bc * ef;                   // level[f+1]
                // off-by-one in f only occurs at a level boundary where both
                // candidate pairs contain the true nearest level -> safe.
                float qv = (w - lo < hi - w) ? lo : hi;
                a[e] = f2bf_rne(qv);
            }
            afr[h * 4 + s4] = a;
        }
    }

    // ---- B (x) + MFMA: 8 batch-tiles of 16, K = 256 in 8 steps ----
    f32x4 acc[8];
    #pragma unroll
    for (int mt = 0; mt < 8; ++mt) acc[mt] = (f32x4){0.f, 0.f, 0.f, 0.f};

    const short* xb = xbf + (size_t)l15 * 4096 + j * 256 + l4 * 8;
    const float* xf = x   + (size_t)l15 * 4096 + j * 256 + l4 * 8;

    #pragma unroll
    for (int s = 0; s < 8; ++s) {
        #pragma unroll
        for (int mt = 0; mt < 8; ++mt) {
            bf16x8 bfr;
            if (XBF) {
                bfr = *(const bf16x8*)(xb + (size_t)mt * 65536 + s * 32);
            } else {
                const float* p = xf + (size_t)mt * 65536 + s * 32;
                f32x4 v0 = *(const f32x4*)p;
                f32x4 v1 = *(const f32x4*)(p + 4);
                bfr[0] = f2bf_rne(v0[0]); bfr[1] = f2bf_rne(v0[1]);
                bfr[2] = f2bf_rne(v0[2]); bfr[3] = f2bf_rne(v0[3]);
                bfr[4] = f2bf_rne(v1[0]); bfr[5] = f2bf_rne(v1[1]);
                bfr[6] = f2bf_rne(v1[2]); bfr[7] = f2bf_rne(v1[3]);
            }
            acc[mt] = __builtin_amdgcn_mfma_f32_16x16x32_bf16(afr[s], bfr, acc[mt], 0, 0, 0);
        }
    }

    // ---- store: D row = l4*4+v = k offset, col = l15 = b offset ----
    #pragma unroll
    for (int mt = 0; mt < 8; ++mt) {
        int b = mt * 16 + l15;
        size_t o = (((size_t)((b * 16 + i) * 16 + j)) << 8) + k0 + (l4 << 2);
        *(f32x4*)(out + o) = acc[mt];
    }
}

extern "C" void kernel_launch(void* const* d_in, const int* in_sizes, int n_in,
                              void* d_out, int out_size, void* d_ws, size_t ws_size,
                              hipStream_t stream) {
    const float* x     = (const float*)d_in[0];
    const float* cores = (const float*)d_in[1];
    float* out = (float*)d_out;

    const size_t xbytes = (size_t)128 * 4096 * sizeof(short);  // 1 MB
    if (ws_size >= xbytes) {
        short* xbf = (short*)d_ws;
        xcvt<<<dim3(256), dim3(256), 0, stream>>>(x, xbf);
        bd_fused<true><<<dim3(1024), dim3(256), 0, stream>>>(x, xbf, cores, out);
    } else {
        bd_fused<false><<<dim3(1024), dim3(256), 0, stream>>>(x, nullptr, cores, out);
    }
}

// Round 5
// 37.211 us; speedup vs baseline: 1.3846x; 1.3846x over previous
//
#include <hip/hip_runtime.h>
#include <hip/hip_bf16.h>
#include <math.h>

// BlockwiseDense: y[b,i,j,k] = sum_l quant(relu(cores[i,j,k,l])) * x[b, j*256+l]
// x: (128, 4096) f32, cores: (16,16,256,256) f32, out: (128,16,16,256) f32.
//
// v4: v2 structure with doubled occupancy.
//   - 32 k-rows per WG -> LDS 16 KB -> grid 2048, __launch_bounds__(256,8):
//     up to 8 WG/CU = 32 waves/CU (v1/v2 were LDS-capped at 4 WG/CU).
//   - analytic quantize (exp2 level pair): no LUT, no LDS gathers, 1 barrier.
//   - x pre-converted to bf16 in d_ws: B-frag = one 16B load, no cvt chain.
//   - contiguous W staging (1 KB/wave/instr), XOR-swizzled LDS tile.

typedef __attribute__((ext_vector_type(4))) float f32x4;
typedef __attribute__((ext_vector_type(8))) short bf16x8;  // 8 bf16
typedef __attribute__((ext_vector_type(8))) short s16x8;
typedef __attribute__((ext_vector_type(4))) short s16x4;

#define TAU   0.75f
#define G_INF 2.0f
#define G_MIN 0.001f

__device__ __forceinline__ short f2bf_rne(float f) {
    union { float f; unsigned u; } v; v.f = f;
    unsigned u = v.u;
    return (short)((u + 0x7FFFu + ((u >> 16) & 1u)) >> 16);
}

// ---- kernel 1: x f32 -> bf16 (1 MB, L2-resident thereafter) ----
__global__ __launch_bounds__(256)
void xcvt(const float* __restrict__ xin, short* __restrict__ xbf) {
    int idx = (blockIdx.x * 256 + threadIdx.x) * 8;
    f32x4 a = *(const f32x4*)(xin + idx);
    f32x4 b = *(const f32x4*)(xin + idx + 4);
    s16x8 o;
    o[0] = f2bf_rne(a[0]); o[1] = f2bf_rne(a[1]);
    o[2] = f2bf_rne(a[2]); o[3] = f2bf_rne(a[3]);
    o[4] = f2bf_rne(b[0]); o[5] = f2bf_rne(b[1]);
    o[6] = f2bf_rne(b[2]); o[7] = f2bf_rne(b[3]);
    *(s16x8*)(xbf + idx) = o;
}

// ---- kernel 2: fused quantize + blockwise GEMM ----
template<bool XBF>
__global__ __launch_bounds__(256, 8)
void bd_fused(const float* __restrict__ x,
              const short* __restrict__ xbf,
              const float* __restrict__ cores,
              float* __restrict__ out)
{
    __shared__ unsigned char wq[32 * 512];  // 32 rows x 256 bf16, XOR-swizzled

    const int tid  = threadIdx.x;
    const int wave = tid >> 6;
    const int lane = tid & 63;
    const int l15  = lane & 15;
    const int l4   = lane >> 4;

    const int bid = blockIdx.x;
    const int ns  = bid & 7;          // which 32-k slice
    const int j   = (bid >> 3) & 15;  // input block
    const int i   = bid >> 7;         // output block
    const int k0  = ns * 32;

    // quantization constants (f32 op order mirrors the numpy reference)
    const float scale     = (G_INF - G_MIN) / (1.0f - expf(-TAU));
    const float inv_scale = 1.0f / scale;
    const float kn = -(255.0f / TAU) * 0.69314718055994531f;   // n = kn*log2(t)
    const float c2 = -(TAU / 255.0f) * 1.44269504088896341f;   // e_f = exp2(c2*f)
    const float Ac = G_MIN + scale;                            // lo = Ac - scale*e_f
    const float Bc = scale * (1.0f - expf(-TAU / 255.0f));     // hi = lo + Bc*e_f

    // ---- stage + quantize W tile: rows k0..k0+31, contiguous loads ----
    const float* wsrc = cores + (((size_t)(i * 16 + j)) << 16) + ((size_t)k0 << 8);
    #pragma unroll
    for (int it = 0; it < 8; ++it) {
        int e = it * 1024 + tid * 4;            // wave covers 1KB contiguous
        f32x4 v = *(const f32x4*)(wsrc + e);
        s16x4 q;
        #pragma unroll
        for (int c = 0; c < 4; ++c) {
            float w = fmaxf(v[c], 0.0f);
            float t = 1.0f - (w - G_MIN) * inv_scale;  // = exp(-tau*n/255)
            t = fmaxf(t, 1e-8f);
            float nr = kn * __log2f(t);
            int f = (int)floorf(nr);
            f = f < 0 ? 0 : (f > 254 ? 254 : f);
            float ef = exp2f(c2 * (float)f);           // v_exp_f32
            float lo = Ac - scale * ef;                // level[f]
            float hi = lo + Bc * ef;                   // level[f+1]
            // off-by-one in f only occurs at a level boundary where both
            // candidate pairs contain the true nearest level -> safe.
            float qv = (w - lo < hi - w) ? lo : hi;
            q[c] = f2bf_rne(qv);
        }
        int r   = e >> 8;                // local k row
        int kb  = (e & 255) * 2;         // byte offset within row (l dim)
        int off = (r * 512 + kb) ^ ((r & 7) << 4);  // bank swizzle
        *(s16x4*)(wq + off) = q;         // ds_write_b64, 2-way max (free)
    }
    __syncthreads();

    // ---- MFMA: wave = 32 batch rows x 32 k-rows, K = 256 in 8 steps ----
    const int brow0 = wave * 32;

    f32x4 acc[2][2];   // [nt: k-sub][mt: batch-sub]
    #pragma unroll
    for (int nt = 0; nt < 2; ++nt)
        #pragma unroll
        for (int mt = 0; mt < 2; ++mt)
            acc[nt][mt] = (f32x4){0.f, 0.f, 0.f, 0.f};

    // B-frag (x): lane holds col = batch b = brow0+mt*16+l15, k-elems l4*8+e
    const short* xb = xbf + (size_t)(brow0 + l15) * 4096 + j * 256 + l4 * 8;
    const float* xf = x   + (size_t)(brow0 + l15) * 4096 + j * 256 + l4 * 8;

    #pragma unroll
    for (int s = 0; s < 8; ++s) {
        bf16x8 bfr[2];
        #pragma unroll
        for (int mt = 0; mt < 2; ++mt) {
            if (XBF) {
                bfr[mt] = *(const bf16x8*)(xb + (size_t)mt * 65536 + s * 32);
            } else {
                const float* p = xf + (size_t)mt * 65536 + s * 32;
                f32x4 v0 = *(const f32x4*)p;
                f32x4 v1 = *(const f32x4*)(p + 4);
                bf16x8 b;
                b[0] = f2bf_rne(v0[0]); b[1] = f2bf_rne(v0[1]);
                b[2] = f2bf_rne(v0[2]); b[3] = f2bf_rne(v0[3]);
                b[4] = f2bf_rne(v1[0]); b[5] = f2bf_rne(v1[1]);
                b[6] = f2bf_rne(v1[2]); b[7] = f2bf_rne(v1[3]);
                bfr[mt] = b;
            }
        }
        #pragma unroll
        for (int nt = 0; nt < 2; ++nt) {
            // A-frag (W): lane holds row = k = nt*16+l15, k-elems l4*8+e
            int r   = nt * 16 + l15;
            int off = (r * 512 + s * 64 + l4 * 16) ^ ((r & 7) << 4);
            bf16x8 afr = *(const bf16x8*)(wq + off);  // ds_read_b128, swizzled
            acc[nt][0] = __builtin_amdgcn_mfma_f32_16x16x32_bf16(afr, bfr[0], acc[nt][0], 0, 0, 0);
            acc[nt][1] = __builtin_amdgcn_mfma_f32_16x16x32_bf16(afr, bfr[1], acc[nt][1], 0, 0, 0);
        }
    }

    // ---- store: D row = l4*4+v = k offset, col = l15 = b offset ----
    // each instr: 16 b-rows x 64B contiguous (4 lanes, l4=0..3, cover k 0..15)
    #pragma unroll
    for (int nt = 0; nt < 2; ++nt) {
        #pragma unroll
        for (int mt = 0; mt < 2; ++mt) {
            int b  = brow0 + mt * 16 + l15;
            int kg = k0 + nt * 16 + (l4 << 2);
            *(f32x4*)(out + (((size_t)((b * 16 + i) * 16 + j)) << 8) + kg) = acc[nt][mt];
        }
    }
}

extern "C" void kernel_launch(void* const* d_in, const int* in_sizes, int n_in,
                              void* d_out, int out_size, void* d_ws, size_t ws_size,
                              hipStream_t stream) {
    const float* x     = (const float*)d_in[0];
    const float* cores = (const float*)d_in[1];
    float* out = (float*)d_out;

    const size_t xbytes = (size_t)128 * 4096 * sizeof(short);  // 1 MB
    if (ws_size >= xbytes) {
        short* xbf = (short*)d_ws;
        xcvt<<<dim3(256), dim3(256), 0, stream>>>(x, xbf);
        bd_fused<true><<<dim3(2048), dim3(256), 0, stream>>>(x, xbf, cores, out);
    } else {
        bd_fused<false><<<dim3(2048), dim3(256), 0, stream>>>(x, nullptr, cores, out);
    }
}